// Round 1
// baseline (488.559 us; speedup 1.0000x reference)
//
#include <hip/hip_runtime.h>
#include <hip/hip_bf16.h>
#include <math.h>

#define CC 1024
#define BB 16
#define DD 128
#define NEGV -1e30f

typedef __attribute__((ext_vector_type(4))) float floatx4;
typedef __attribute__((ext_vector_type(8))) __bf16 bf16x8;

__device__ __forceinline__ unsigned short f2bf(float x) {
    unsigned int u = __float_as_uint(x);
    u = (u + 0x7FFFu + ((u >> 16) & 1u)) >> 16;
    return (unsigned short)u;
}

// ---------------- prep: h (c,b,d) fp32 -> h_bc (b,c,d) bf16, h_bT (b,d,c) bf16
__global__ __launch_bounds__(256) void prep_h(const float* __restrict__ h,
                                              unsigned short* __restrict__ h_bc,
                                              unsigned short* __restrict__ h_bT) {
    __shared__ float tile[64][65];
    const int c0 = blockIdx.x * 64, d0 = blockIdx.y * 64, b = blockIdx.z;
    const int tx = threadIdx.x & 63, ty = threadIdx.x >> 6;
#pragma unroll
    for (int i = 0; i < 16; i++) {
        int cl = ty + i * 4;
        float v = h[((size_t)(c0 + cl) * BB + b) * DD + d0 + tx];
        tile[cl][tx] = v;
        h_bc[((size_t)b * CC + c0 + cl) * DD + d0 + tx] = f2bf(v);
    }
    __syncthreads();
#pragma unroll
    for (int i = 0; i < 16; i++) {
        int dl = ty + i * 4;
        h_bT[((size_t)b * DD + d0 + dl) * CC + c0 + tx] = f2bf(tile[tx][dl]);
    }
}

// ---------------- prep: cast weights to bf16
__global__ __launch_bounds__(256) void prep_w(const float* __restrict__ w1, const float* __restrict__ w2,
                                              const float* __restrict__ wr, const float* __restrict__ wg,
                                              unsigned short* __restrict__ o1, unsigned short* __restrict__ o2,
                                              unsigned short* __restrict__ owr, unsigned short* __restrict__ owg) {
    int i = blockIdx.x * 256 + threadIdx.x;
    if (i < DD * DD) { o1[i] = f2bf(w1[i]); o2[i] = f2bf(w2[i]); }
    if (i < DD * 4 * DD) { owr[i] = f2bf(wr[i]); owg[i] = f2bf(wg[i]); }
}

// ---------------- shared GEMM helpers ----------------
// stage ROWS x 64 bf16 tile into LDS; src points at (row0, k0); ld in elements
template <int ROWS>
__device__ __forceinline__ void stage_tile(unsigned short (*dst)[64], const unsigned short* src, int ld) {
    constexpr int CH = ROWS * 8;  // 16B chunks
#pragma unroll
    for (int ch = threadIdx.x; ch < CH; ch += 256) {
        int r = ch >> 3, c = ch & 7;
        *(int4*)(&dst[r][c * 8]) = *(const int4*)(src + (size_t)r * ld + c * 8);
    }
}

// wave computes TM x TN grid of 16x16 tiles over one BK=64 LDS tile
template <int TM, int TN>
__device__ __forceinline__ void mfma_tile(const unsigned short (*As)[64], const unsigned short (*Bs)[64],
                                          int arow0, int bcol0, floatx4 (&acc)[TM][TN]) {
    const int lane = threadIdx.x & 63;
    const int l16 = lane & 15, quad = lane >> 4;
#pragma unroll
    for (int kk = 0; kk < 2; ++kk) {
        bf16x8 a[TM], b[TN];
#pragma unroll
        for (int tm = 0; tm < TM; tm++)
            a[tm] = *(const bf16x8*)(&As[arow0 + tm * 16 + l16][kk * 32 + quad * 8]);
#pragma unroll
        for (int tn = 0; tn < TN; tn++)
            b[tn] = *(const bf16x8*)(&Bs[bcol0 + tn * 16 + l16][kk * 32 + quad * 8]);
#pragma unroll
        for (int tm = 0; tm < TM; tm++)
#pragma unroll
            for (int tn = 0; tn < TN; tn++)
                acc[tm][tn] = __builtin_amdgcn_mfma_f32_16x16x32_bf16(a[tm], b[tn], acc[tm][tn], 0, 0, 0);
    }
}

// ---------------- h1/h2: relu(h_bc @ W^T + bias), M=16384 N=128 K=128; z picks W1/W2
__global__ __launch_bounds__(256) void gemm_h12(const unsigned short* __restrict__ h_bc,
                                                const unsigned short* __restrict__ w1t,
                                                const unsigned short* __restrict__ w2t,
                                                const float* __restrict__ b1, const float* __restrict__ b2,
                                                unsigned short* __restrict__ h1, unsigned short* __restrict__ h2) {
    __shared__ unsigned short As[128][64];
    __shared__ unsigned short Bs[128][64];
    const unsigned short* W = blockIdx.z ? w2t : w1t;
    const float* bias = blockIdx.z ? b2 : b1;
    unsigned short* out = blockIdx.z ? h2 : h1;
    const int r0 = blockIdx.x * 128;
    const int w = threadIdx.x >> 6, lane = threadIdx.x & 63;
    const int wm = (w >> 1) * 64, wn = (w & 1) * 64;
    floatx4 acc[4][4] = {};
    for (int k0 = 0; k0 < DD; k0 += 64) {
        stage_tile<128>(As, h_bc + (size_t)r0 * DD + k0, DD);
        stage_tile<128>(Bs, W + k0, DD);
        __syncthreads();
        mfma_tile<4, 4>(As, Bs, wm, wn, acc);
        __syncthreads();
    }
    const int quad = lane >> 4, l16 = lane & 15;
#pragma unroll
    for (int tm = 0; tm < 4; tm++)
#pragma unroll
        for (int tn = 0; tn < 4; tn++)
#pragma unroll
            for (int i = 0; i < 4; i++) {
                int row = r0 + wm + tm * 16 + quad * 4 + i;
                int col = wn + tn * 16 + l16;
                float v = acc[tm][tn][i] + bias[col];
                v = fmaxf(v, 0.f);
                out[(size_t)row * DD + col] = f2bf(v);
            }
}

// ---------------- masked row softmax (axis=2): one block per (b,i) row; bf16 out
__global__ __launch_bounds__(256) void softmax_row(const float* __restrict__ src, const int* __restrict__ mask,
                                                   unsigned short* __restrict__ dst) {
    const int b = blockIdx.y, i = blockIdx.x;
    const float* row = src + ((size_t)b * CC + i) * CC;
    const int t = threadIdx.x;
    float x[4];
    float mx = -3.0e38f;
#pragma unroll
    for (int u = 0; u < 4; u++) {
        int j = t + u * 256;
        float v = row[j];
        if (mask[b * CC + j] == 0) v = NEGV;
        x[u] = v;
        mx = fmaxf(mx, v);
    }
    __shared__ float rm[4], rs[4];
    const int w = t >> 6, lane = t & 63;
#pragma unroll
    for (int off = 32; off; off >>= 1) mx = fmaxf(mx, __shfl_xor(mx, off, 64));
    if (lane == 0) rm[w] = mx;
    __syncthreads();
    mx = fmaxf(fmaxf(rm[0], rm[1]), fmaxf(rm[2], rm[3]));
    float e[4], s = 0.f;
#pragma unroll
    for (int u = 0; u < 4; u++) { e[u] = expf(x[u] - mx); s += e[u]; }
#pragma unroll
    for (int off = 32; off; off >>= 1) s += __shfl_xor(s, off, 64);
    if (lane == 0) rs[w] = s;
    __syncthreads();
    s = rs[0] + rs[1] + rs[2] + rs[3];
    float inv = 1.f / s;
#pragma unroll
    for (int u = 0; u < 4; u++) dst[((size_t)b * CC + i) * CC + t + u * 256] = f2bf(e[u] * inv);
}

// ---------------- masked column softmax (axis=1) + transpose: out (b, j, i) bf16
__global__ __launch_bounds__(256) void softmax_colT(const float* __restrict__ B_t, const int* __restrict__ mask,
                                                    unsigned short* __restrict__ out) {
    const int b = blockIdx.y, j0 = blockIdx.x * 64;
    const int tx = threadIdx.x & 63, ty = threadIdx.x >> 6;
    const float* Bb = B_t + (size_t)b * CC * CC;
    // pass 1: online max/sum per column j = j0+tx, strip over i = ty::4
    float mx = -3.0e38f, sm = 0.f;
    for (int i = ty; i < CC; i += 4) {
        float v = Bb[(size_t)i * CC + j0 + tx];
        if (mask[b * CC + i] == 0) v = NEGV;
        float nm = fmaxf(mx, v);
        sm = sm * expf(mx - nm) + expf(v - nm);
        mx = nm;
    }
    __shared__ float smx[4][64], ssm[4][64];
    smx[ty][tx] = mx;
    ssm[ty][tx] = sm;
    __syncthreads();
    float fm = -3.0e38f;
#pragma unroll
    for (int q = 0; q < 4; q++) fm = fmaxf(fm, smx[q][tx]);
    float fs = 0.f;
#pragma unroll
    for (int q = 0; q < 4; q++) fs += ssm[q][tx] * expf(smx[q][tx] - fm);
    const float inv = 1.f / fs;
    // pass 2: 64x64 tiles, coalesced read, transposed coalesced write
    __shared__ float tile[64][65];
    for (int it = 0; it < 16; ++it) {
        int i0 = it * 64;
        __syncthreads();
        for (int r = ty; r < 64; r += 4) {
            int i = i0 + r;
            float v = Bb[(size_t)i * CC + j0 + tx];
            if (mask[b * CC + i] == 0) v = NEGV;
            tile[r][tx] = expf(v - fm) * inv;  // fm/inv are per-tx (per j)
        }
        __syncthreads();
        for (int r = ty; r < 64; r += 4)
            out[((size_t)b * CC + j0 + r) * CC + i0 + tx] = f2bf(tile[tx][r]);
    }
}

// ---------------- B_new = h1@h2^T + gamma * Bt2@Bt1, per batch, 128x128 tiles
__global__ __launch_bounds__(256) void gemm_bnew(const unsigned short* __restrict__ Bt2,
                                                 const unsigned short* __restrict__ Bt1T,
                                                 const unsigned short* __restrict__ h1,
                                                 const unsigned short* __restrict__ h2,
                                                 const float* __restrict__ gp, float* __restrict__ Bnew) {
    __shared__ unsigned short As[128][64];
    __shared__ unsigned short Bs[128][64];
    const int b = blockIdx.z;
    const int i0 = blockIdx.x * 128, j0 = blockIdx.y * 128;
    const unsigned short* A1 = Bt2 + (size_t)b * CC * CC + (size_t)i0 * CC;
    const unsigned short* B1 = Bt1T + (size_t)b * CC * CC + (size_t)j0 * CC;
    const unsigned short* A2 = h1 + (size_t)b * CC * DD + (size_t)i0 * DD;
    const unsigned short* B2 = h2 + (size_t)b * CC * DD + (size_t)j0 * DD;
    const int w = threadIdx.x >> 6, lane = threadIdx.x & 63;
    const int wm = (w >> 1) * 64, wn = (w & 1) * 64;
    floatx4 acc[4][4] = {};
    for (int k0 = 0; k0 < CC; k0 += 64) {  // B_1 accumulation, K=1024
        stage_tile<128>(As, A1 + k0, CC);
        stage_tile<128>(Bs, B1 + k0, CC);
        __syncthreads();
        mfma_tile<4, 4>(As, Bs, wm, wn, acc);
        __syncthreads();
    }
    const float gm = gp[0];
#pragma unroll
    for (int tm = 0; tm < 4; tm++)
#pragma unroll
        for (int tn = 0; tn < 4; tn++) acc[tm][tn] *= gm;
    for (int k0 = 0; k0 < DD; k0 += 64) {  // B_0 accumulation, K=128
        stage_tile<128>(As, A2 + k0, DD);
        stage_tile<128>(Bs, B2 + k0, DD);
        __syncthreads();
        mfma_tile<4, 4>(As, Bs, wm, wn, acc);
        __syncthreads();
    }
    const int quad = lane >> 4, l16 = lane & 15;
    float* out = Bnew + (size_t)b * CC * CC;
#pragma unroll
    for (int tm = 0; tm < 4; tm++)
#pragma unroll
        for (int tn = 0; tn < 4; tn++)
#pragma unroll
            for (int i = 0; i < 4; i++) {
                int row = i0 + wm + tm * 16 + quad * 4 + i;
                int col = j0 + wn + tn * 16 + l16;
                float v = acc[tm][tn][i];
                if (row == col) v = 0.f;  // diag zeroed
                out[(size_t)row * CC + col] = v;
            }
}

// ---------------- h_tmp = Btt @ h_bT^T (per b, M=1024 N=128 K=1024) + build m
__global__ __launch_bounds__(256) void gemm_htmp(const unsigned short* __restrict__ Btt,
                                                 const unsigned short* __restrict__ h_bT,
                                                 const float* __restrict__ h, unsigned short* __restrict__ mbuf) {
    __shared__ unsigned short As[64][64];
    __shared__ unsigned short Bs[128][64];
    const int b = blockIdx.z;
    const int i0 = blockIdx.x * 64;
    const unsigned short* A = Btt + (size_t)b * CC * CC + (size_t)i0 * CC;
    const unsigned short* Bt = h_bT + (size_t)b * DD * CC;
    const int w = threadIdx.x >> 6, lane = threadIdx.x & 63;
    const int wm = (w >> 1) * 32, wn = (w & 1) * 64;
    floatx4 acc[2][4] = {};
    for (int k0 = 0; k0 < CC; k0 += 64) {
        stage_tile<64>(As, A + k0, CC);
        stage_tile<128>(Bs, Bt + k0, CC);
        __syncthreads();
        mfma_tile<2, 4>(As, Bs, wm, wn, acc);
        __syncthreads();
    }
    const int quad = lane >> 4, l16 = lane & 15;
#pragma unroll
    for (int tm = 0; tm < 2; tm++)
#pragma unroll
        for (int tn = 0; tn < 4; tn++)
#pragma unroll
            for (int i = 0; i < 4; i++) {
                int ig = i0 + wm + tm * 16 + quad * 4 + i;
                int d = wn + tn * 16 + l16;
                float ht = acc[tm][tn][i];
                float hv = h[((size_t)ig * BB + b) * DD + d];
                unsigned short* mrow = mbuf + ((size_t)b * CC + ig) * (4 * DD);
                mrow[d] = f2bf(hv);
                mrow[DD + d] = f2bf(ht);
                mrow[2 * DD + d] = f2bf(hv * ht);
                mrow[3 * DD + d] = f2bf(hv - ht);
            }
}

// ---------------- x = relu(m @ Wr^T): M=16384 N=128 K=512 -> x_ws fp32
__global__ __launch_bounds__(256) void gemm_x(const unsigned short* __restrict__ mbuf,
                                              const unsigned short* __restrict__ wrt, float* __restrict__ x_ws) {
    __shared__ unsigned short As[64][64];
    __shared__ unsigned short Bs[128][64];
    const int r0 = blockIdx.x * 64;
    const unsigned short* A = mbuf + (size_t)r0 * (4 * DD);
    const int w = threadIdx.x >> 6, lane = threadIdx.x & 63;
    const int wm = (w >> 1) * 32, wn = (w & 1) * 64;
    floatx4 acc[2][4] = {};
    for (int k0 = 0; k0 < 4 * DD; k0 += 64) {
        stage_tile<64>(As, A + k0, 4 * DD);
        stage_tile<128>(Bs, wrt + k0, 4 * DD);
        __syncthreads();
        mfma_tile<2, 4>(As, Bs, wm, wn, acc);
        __syncthreads();
    }
    const int quad = lane >> 4, l16 = lane & 15;
#pragma unroll
    for (int tm = 0; tm < 2; tm++)
#pragma unroll
        for (int tn = 0; tn < 4; tn++)
#pragma unroll
            for (int i = 0; i < 4; i++) {
                int r = r0 + wm + tm * 16 + quad * 4 + i;
                int d = wn + tn * 16 + l16;
                x_ws[(size_t)r * DD + d] = fmaxf(acc[tm][tn][i], 0.f);
            }
}

// ---------------- g = sigmoid(m @ Wg^T); o = x*g + (1-g)*h -> d_out (c,b,d)
__global__ __launch_bounds__(256) void gemm_go(const unsigned short* __restrict__ mbuf,
                                               const unsigned short* __restrict__ wgt,
                                               const float* __restrict__ x_ws, const float* __restrict__ h,
                                               float* __restrict__ o) {
    __shared__ unsigned short As[64][64];
    __shared__ unsigned short Bs[128][64];
    const int r0 = blockIdx.x * 64;
    const unsigned short* A = mbuf + (size_t)r0 * (4 * DD);
    const int w = threadIdx.x >> 6, lane = threadIdx.x & 63;
    const int wm = (w >> 1) * 32, wn = (w & 1) * 64;
    floatx4 acc[2][4] = {};
    for (int k0 = 0; k0 < 4 * DD; k0 += 64) {
        stage_tile<64>(As, A + k0, 4 * DD);
        stage_tile<128>(Bs, wgt + k0, 4 * DD);
        __syncthreads();
        mfma_tile<2, 4>(As, Bs, wm, wn, acc);
        __syncthreads();
    }
    const int quad = lane >> 4, l16 = lane & 15;
#pragma unroll
    for (int tm = 0; tm < 2; tm++)
#pragma unroll
        for (int tn = 0; tn < 4; tn++)
#pragma unroll
            for (int i = 0; i < 4; i++) {
                int r = r0 + wm + tm * 16 + quad * 4 + i;
                int d = wn + tn * 16 + l16;
                int bb = r >> 10, c = r & 1023;
                float g = 1.f / (1.f + expf(-acc[tm][tn][i]));
                float xv = x_ws[(size_t)r * DD + d];
                float hv = h[((size_t)c * BB + bb) * DD + d];
                o[((size_t)c * BB + bb) * DD + d] = xv * g + (1.f - g) * hv;
            }
}

extern "C" void kernel_launch(void* const* d_in, const int* in_sizes, int n_in,
                              void* d_out, int out_size, void* d_ws, size_t ws_size,
                              hipStream_t stream) {
    const float* h = (const float*)d_in[0];
    const int* h_mask = (const int*)d_in[1];
    const float* B_t = (const float*)d_in[2];
    const float* W1w = (const float*)d_in[3];
    const float* W1b = (const float*)d_in[4];
    const float* W2w = (const float*)d_in[5];
    const float* W2b = (const float*)d_in[6];
    const float* gp = (const float*)d_in[7];
    const float* Wrw = (const float*)d_in[8];
    const float* Wgw = (const float*)d_in[9];
    float* o = (float*)d_out;
    float* Bnew = o + (size_t)CC * BB * DD;  // output 1 region

    char* ws = (char*)d_ws;
    size_t off = 0;
    auto alloc = [&](size_t bytes) { void* p = ws + off; off += bytes; return p; };
    unsigned short* h_bc = (unsigned short*)alloc((size_t)BB * CC * DD * 2);
    unsigned short* h_bT = (unsigned short*)alloc((size_t)BB * DD * CC * 2);
    unsigned short* h1 = (unsigned short*)alloc((size_t)BB * CC * DD * 2);
    unsigned short* h2 = (unsigned short*)alloc((size_t)BB * CC * DD * 2);
    unsigned short* w1t = (unsigned short*)alloc((size_t)DD * DD * 2);
    unsigned short* w2t = (unsigned short*)alloc((size_t)DD * DD * 2);
    unsigned short* wrt = (unsigned short*)alloc((size_t)DD * 4 * DD * 2);
    unsigned short* wgt = (unsigned short*)alloc((size_t)DD * 4 * DD * 2);
    unsigned short* Bt2 = (unsigned short*)alloc((size_t)BB * CC * CC * 2);
    unsigned short* Bt1T = (unsigned short*)alloc((size_t)BB * CC * CC * 2);
    unsigned short* Btt = (unsigned short*)alloc((size_t)BB * CC * CC * 2);
    unsigned short* mbuf = (unsigned short*)alloc((size_t)BB * CC * 4 * DD * 2);
    float* x_ws = (float*)alloc((size_t)BB * CC * DD * 4);

    prep_h<<<dim3(16, 2, 16), 256, 0, stream>>>(h, h_bc, h_bT);
    prep_w<<<dim3(256), 256, 0, stream>>>(W1w, W2w, Wrw, Wgw, w1t, w2t, wrt, wgt);
    gemm_h12<<<dim3(128, 1, 2), 256, 0, stream>>>(h_bc, w1t, w2t, W1b, W2b, h1, h2);
    softmax_row<<<dim3(1024, 16), 256, 0, stream>>>(B_t, h_mask, Bt2);        // axis=2 -> Bt2 (b,i,k)
    softmax_colT<<<dim3(16, 16), 256, 0, stream>>>(B_t, h_mask, Bt1T);        // axis=1, transposed -> (b,j,k)
    gemm_bnew<<<dim3(8, 8, 16), 256, 0, stream>>>(Bt2, Bt1T, h1, h2, gp, Bnew);
    softmax_row<<<dim3(1024, 16), 256, 0, stream>>>(Bnew, h_mask, Btt);       // axis=2 on B_new
    gemm_htmp<<<dim3(16, 1, 16), 256, 0, stream>>>(Btt, h_bT, h, mbuf);
    gemm_x<<<dim3(256), 256, 0, stream>>>(mbuf, wrt, x_ws);
    gemm_go<<<dim3(256), 256, 0, stream>>>(mbuf, wgt, x_ws, h, o);
}

// Round 2
// 302.950 us; speedup vs baseline: 1.6127x; 1.6127x over previous
//
#include <hip/hip_runtime.h>
#include <hip/hip_bf16.h>
#include <math.h>

#define CC 1024
#define BB 16
#define DD 128
#define NEGV -1e30f

typedef __attribute__((ext_vector_type(4))) float floatx4;
typedef __attribute__((ext_vector_type(8))) __bf16 bf16x8;

__device__ __forceinline__ unsigned short f2bf(float x) {
    unsigned int u = __float_as_uint(x);
    u = (u + 0x7FFFu + ((u >> 16) & 1u)) >> 16;
    return (unsigned short)u;
}
__device__ __forceinline__ float bf2f(unsigned short v) {
    return __uint_as_float((unsigned int)v << 16);
}

// ---------------- prep: h (c,b,d) fp32 -> h_bc (b,c,d) bf16, h_bT (b,d,c) bf16
__global__ __launch_bounds__(256) void prep_h(const float* __restrict__ h,
                                              unsigned short* __restrict__ h_bc,
                                              unsigned short* __restrict__ h_bT) {
    __shared__ float tile[64][65];
    const int c0 = blockIdx.x * 64, d0 = blockIdx.y * 64, b = blockIdx.z;
    const int tx = threadIdx.x & 63, ty = threadIdx.x >> 6;
#pragma unroll
    for (int i = 0; i < 16; i++) {
        int cl = ty + i * 4;
        float v = h[((size_t)(c0 + cl) * BB + b) * DD + d0 + tx];
        tile[cl][tx] = v;
        h_bc[((size_t)b * CC + c0 + cl) * DD + d0 + tx] = f2bf(v);
    }
    __syncthreads();
#pragma unroll
    for (int i = 0; i < 16; i++) {
        int dl = ty + i * 4;
        h_bT[((size_t)b * DD + d0 + dl) * CC + c0 + tx] = f2bf(tile[tx][dl]);
    }
}

// ---------------- prep: cast weights to bf16
__global__ __launch_bounds__(256) void prep_w(const float* __restrict__ w1, const float* __restrict__ w2,
                                              const float* __restrict__ wr, const float* __restrict__ wg,
                                              unsigned short* __restrict__ o1, unsigned short* __restrict__ o2,
                                              unsigned short* __restrict__ owr, unsigned short* __restrict__ owg) {
    int i = blockIdx.x * 256 + threadIdx.x;
    if (i < DD * DD) { o1[i] = f2bf(w1[i]); o2[i] = f2bf(w2[i]); }
    if (i < DD * 4 * DD) { owr[i] = f2bf(wr[i]); owg[i] = f2bf(wg[i]); }
}

// ---------------- transpose B_t (b,i,j) fp32 -> (b,j,i) bf16
__global__ __launch_bounds__(256) void transpose_bt(const float* __restrict__ B_t,
                                                    unsigned short* __restrict__ out) {
    __shared__ float tile[64][65];
    const int b = blockIdx.z, i0 = blockIdx.x * 64, j0 = blockIdx.y * 64;
    const int tx = threadIdx.x & 63, ty = threadIdx.x >> 6;
    const float* src = B_t + (size_t)b * CC * CC;
    unsigned short* dst = out + (size_t)b * CC * CC;
#pragma unroll
    for (int r = ty; r < 64; r += 4) tile[r][tx] = src[(size_t)(i0 + r) * CC + j0 + tx];
    __syncthreads();
#pragma unroll
    for (int r = ty; r < 64; r += 4)
        dst[(size_t)(j0 + r) * CC + i0 + tx] = f2bf(tile[tx][r]);
}

// ---------------- async staging: ROWS x 64 bf16 tile, XOR-swizzled chunk layout.
// LDS chunk (r,c) holds global (r, c ^ (r&7)); global_load_lds needs LDS dest
// contiguous in lane order, so we permute the SOURCE addresses instead.
template <int ROWS>
__device__ __forceinline__ void stage_async(unsigned short (*dst)[64], const unsigned short* src, int ld) {
    constexpr int CH = ROWS * 8;  // 16B chunks
    const int w = threadIdx.x >> 6, lane = threadIdx.x & 63;
#pragma unroll
    for (int base = w * 64; base < CH; base += 256) {
        int ch = base + lane;
        int r = ch >> 3, c = ch & 7;
        int cg = c ^ (r & 7);
        __builtin_amdgcn_global_load_lds(
            (const __attribute__((address_space(1))) void*)(src + (size_t)r * ld + cg * 8),
            (__attribute__((address_space(3))) void*)(&dst[0][0] + (size_t)base * 8),
            16, 0, 0);
    }
}

// wave computes TM x TN grid of 16x16 tiles over one BK=64 swizzled LDS tile
template <int TM, int TN>
__device__ __forceinline__ void mfma_tile(const unsigned short (*As)[64], const unsigned short (*Bs)[64],
                                          int arow0, int bcol0, floatx4 (&acc)[TM][TN]) {
    const int lane = threadIdx.x & 63;
    const int l16 = lane & 15, quad = lane >> 4;
    const int sw = l16 & 7;  // row&7 for all our (row mult of 16) tiles
#pragma unroll
    for (int kk = 0; kk < 2; ++kk) {
        bf16x8 a[TM], b[TN];
#pragma unroll
        for (int tm = 0; tm < TM; tm++)
            a[tm] = *(const bf16x8*)(&As[arow0 + tm * 16 + l16][((kk * 4 + quad) ^ sw) * 8]);
#pragma unroll
        for (int tn = 0; tn < TN; tn++)
            b[tn] = *(const bf16x8*)(&Bs[bcol0 + tn * 16 + l16][((kk * 4 + quad) ^ sw) * 8]);
#pragma unroll
        for (int tm = 0; tm < TM; tm++)
#pragma unroll
            for (int tn = 0; tn < TN; tn++)
                acc[tm][tn] = __builtin_amdgcn_mfma_f32_16x16x32_bf16(a[tm], b[tn], acc[tm][tn], 0, 0, 0);
    }
}

// ---------------- h1/h2: relu(h_bc @ W^T + bias), M=16384 N=128 K=128; z picks W1/W2
__global__ __launch_bounds__(256) void gemm_h12(const unsigned short* __restrict__ h_bc,
                                                const unsigned short* __restrict__ w1t,
                                                const unsigned short* __restrict__ w2t,
                                                const float* __restrict__ b1, const float* __restrict__ b2,
                                                unsigned short* __restrict__ h1, unsigned short* __restrict__ h2) {
    __shared__ unsigned short As[128][64];
    __shared__ unsigned short Bs[128][64];
    const unsigned short* W = blockIdx.z ? w2t : w1t;
    const float* bias = blockIdx.z ? b2 : b1;
    unsigned short* out = blockIdx.z ? h2 : h1;
    const int r0 = blockIdx.x * 128;
    const int w = threadIdx.x >> 6, lane = threadIdx.x & 63;
    const int wm = (w >> 1) * 64, wn = (w & 1) * 64;
    floatx4 acc[4][4] = {};
    for (int k0 = 0; k0 < DD; k0 += 64) {
        stage_async<128>(As, h_bc + (size_t)r0 * DD + k0, DD);
        stage_async<128>(Bs, W + k0, DD);
        __syncthreads();
        mfma_tile<4, 4>(As, Bs, wm, wn, acc);
        __syncthreads();
    }
    const int quad = lane >> 4, l16 = lane & 15;
#pragma unroll
    for (int tm = 0; tm < 4; tm++)
#pragma unroll
        for (int tn = 0; tn < 4; tn++)
#pragma unroll
            for (int i = 0; i < 4; i++) {
                int row = r0 + wm + tm * 16 + quad * 4 + i;
                int col = wn + tn * 16 + l16;
                float v = acc[tm][tn][i] + bias[col];
                out[(size_t)row * DD + col] = f2bf(fmaxf(v, 0.f));
            }
}

// ---------------- masked row softmax; T = float or unsigned short(bf16 in); bf16 out
__device__ __forceinline__ void load4(const float* p, float* x) {
    float4 v = *(const float4*)p;
    x[0] = v.x; x[1] = v.y; x[2] = v.z; x[3] = v.w;
}
__device__ __forceinline__ void load4(const unsigned short* p, float* x) {
    ushort4 v = *(const ushort4*)p;
    x[0] = bf2f(v.x); x[1] = bf2f(v.y); x[2] = bf2f(v.z); x[3] = bf2f(v.w);
}

template <typename T>
__global__ __launch_bounds__(256) void softmax_row_t(const T* __restrict__ src, const int* __restrict__ mask,
                                                     unsigned short* __restrict__ dst) {
    const int b = blockIdx.y, i = blockIdx.x;
    const int t = threadIdx.x;
    float x[4];
    load4(src + ((size_t)b * CC + i) * CC + t * 4, x);
    const int4 mv = *(const int4*)(mask + b * CC + t * 4);
    if (mv.x == 0) x[0] = NEGV;
    if (mv.y == 0) x[1] = NEGV;
    if (mv.z == 0) x[2] = NEGV;
    if (mv.w == 0) x[3] = NEGV;
    float mx = fmaxf(fmaxf(x[0], x[1]), fmaxf(x[2], x[3]));
    __shared__ float rm[4], rs[4];
    const int w = t >> 6, lane = t & 63;
#pragma unroll
    for (int off = 32; off; off >>= 1) mx = fmaxf(mx, __shfl_xor(mx, off, 64));
    if (lane == 0) rm[w] = mx;
    __syncthreads();
    mx = fmaxf(fmaxf(rm[0], rm[1]), fmaxf(rm[2], rm[3]));
    float e[4], s = 0.f;
#pragma unroll
    for (int u = 0; u < 4; u++) { e[u] = expf(x[u] - mx); s += e[u]; }
#pragma unroll
    for (int off = 32; off; off >>= 1) s += __shfl_xor(s, off, 64);
    if (lane == 0) rs[w] = s;
    __syncthreads();
    s = rs[0] + rs[1] + rs[2] + rs[3];
    const float inv = 1.f / s;
    ushort4 o4;
    o4.x = f2bf(e[0] * inv); o4.y = f2bf(e[1] * inv);
    o4.z = f2bf(e[2] * inv); o4.w = f2bf(e[3] * inv);
    *(ushort4*)(dst + ((size_t)b * CC + i) * CC + t * 4) = o4;
}

// ---------------- B_new = h1@h2^T + gamma * Bt2@Bt1, per batch, 128x128 tiles
__global__ __launch_bounds__(256) void gemm_bnew(const unsigned short* __restrict__ Bt2,
                                                 const unsigned short* __restrict__ Bt1T,
                                                 const unsigned short* __restrict__ h1,
                                                 const unsigned short* __restrict__ h2,
                                                 const float* __restrict__ gp, float* __restrict__ Bnew) {
    __shared__ unsigned short As[128][64];
    __shared__ unsigned short Bs[128][64];
    const int b = blockIdx.z;
    const int i0 = blockIdx.x * 128, j0 = blockIdx.y * 128;
    const unsigned short* A1 = Bt2 + (size_t)b * CC * CC + (size_t)i0 * CC;
    const unsigned short* B1 = Bt1T + (size_t)b * CC * CC + (size_t)j0 * CC;
    const unsigned short* A2 = h1 + (size_t)b * CC * DD + (size_t)i0 * DD;
    const unsigned short* B2 = h2 + (size_t)b * CC * DD + (size_t)j0 * DD;
    const int w = threadIdx.x >> 6, lane = threadIdx.x & 63;
    const int wm = (w >> 1) * 64, wn = (w & 1) * 64;
    floatx4 acc[4][4] = {};
    for (int k0 = 0; k0 < CC; k0 += 64) {  // B_1 accumulation, K=1024
        stage_async<128>(As, A1 + k0, CC);
        stage_async<128>(Bs, B1 + k0, CC);
        __syncthreads();
        mfma_tile<4, 4>(As, Bs, wm, wn, acc);
        __syncthreads();
    }
    const float gm = gp[0];
#pragma unroll
    for (int tm = 0; tm < 4; tm++)
#pragma unroll
        for (int tn = 0; tn < 4; tn++) acc[tm][tn] *= gm;
    for (int k0 = 0; k0 < DD; k0 += 64) {  // B_0 accumulation, K=128
        stage_async<128>(As, A2 + k0, DD);
        stage_async<128>(Bs, B2 + k0, DD);
        __syncthreads();
        mfma_tile<4, 4>(As, Bs, wm, wn, acc);
        __syncthreads();
    }
    const int quad = lane >> 4, l16 = lane & 15;
    float* out = Bnew + (size_t)b * CC * CC;
#pragma unroll
    for (int tm = 0; tm < 4; tm++)
#pragma unroll
        for (int tn = 0; tn < 4; tn++)
#pragma unroll
            for (int i = 0; i < 4; i++) {
                int row = i0 + wm + tm * 16 + quad * 4 + i;
                int col = j0 + wn + tn * 16 + l16;
                float v = acc[tm][tn][i];
                if (row == col) v = 0.f;  // diag zeroed
                out[(size_t)row * CC + col] = v;
            }
}

// ---------------- h_tmp = Btt @ h_bT^T (per b, M=1024 N=128 K=1024) + build m
__global__ __launch_bounds__(256) void gemm_htmp(const unsigned short* __restrict__ Btt,
                                                 const unsigned short* __restrict__ h_bT,
                                                 const float* __restrict__ h, unsigned short* __restrict__ mbuf) {
    __shared__ unsigned short As[64][64];
    __shared__ unsigned short Bs[128][64];
    const int b = blockIdx.z;
    const int i0 = blockIdx.x * 64;
    const unsigned short* A = Btt + (size_t)b * CC * CC + (size_t)i0 * CC;
    const unsigned short* Bt = h_bT + (size_t)b * DD * CC;
    const int w = threadIdx.x >> 6, lane = threadIdx.x & 63;
    const int wm = (w >> 1) * 32, wn = (w & 1) * 64;
    floatx4 acc[2][4] = {};
    for (int k0 = 0; k0 < CC; k0 += 64) {
        stage_async<64>(As, A + k0, CC);
        stage_async<128>(Bs, Bt + k0, CC);
        __syncthreads();
        mfma_tile<2, 4>(As, Bs, wm, wn, acc);
        __syncthreads();
    }
    const int quad = lane >> 4, l16 = lane & 15;
#pragma unroll
    for (int tm = 0; tm < 2; tm++)
#pragma unroll
        for (int tn = 0; tn < 4; tn++)
#pragma unroll
            for (int i = 0; i < 4; i++) {
                int ig = i0 + wm + tm * 16 + quad * 4 + i;
                int d = wn + tn * 16 + l16;
                float ht = acc[tm][tn][i];
                float hv = h[((size_t)ig * BB + b) * DD + d];
                unsigned short* mrow = mbuf + ((size_t)b * CC + ig) * (4 * DD);
                mrow[d] = f2bf(hv);
                mrow[DD + d] = f2bf(ht);
                mrow[2 * DD + d] = f2bf(hv * ht);
                mrow[3 * DD + d] = f2bf(hv - ht);
            }
}

// ---------------- fused gate: x=relu(m@Wr^T), g=sigmoid(m@Wg^T), o=x*g+(1-g)*h
__global__ __launch_bounds__(256) void gemm_gate(const unsigned short* __restrict__ mbuf,
                                                 const unsigned short* __restrict__ wrt,
                                                 const unsigned short* __restrict__ wgt,
                                                 const float* __restrict__ h, float* __restrict__ o) {
    __shared__ unsigned short As[64][64];
    __shared__ unsigned short Br[128][64];
    __shared__ unsigned short Bg[128][64];
    const int r0 = blockIdx.x * 64;
    const unsigned short* A = mbuf + (size_t)r0 * (4 * DD);
    const int w = threadIdx.x >> 6, lane = threadIdx.x & 63;
    const int wm = (w >> 1) * 32, wn = (w & 1) * 64;
    floatx4 accx[2][4] = {};
    floatx4 accg[2][4] = {};
    for (int k0 = 0; k0 < 4 * DD; k0 += 64) {
        stage_async<64>(As, A + k0, 4 * DD);
        stage_async<128>(Br, wrt + k0, 4 * DD);
        stage_async<128>(Bg, wgt + k0, 4 * DD);
        __syncthreads();
        mfma_tile<2, 4>(As, Br, wm, wn, accx);
        mfma_tile<2, 4>(As, Bg, wm, wn, accg);
        __syncthreads();
    }
    const int quad = lane >> 4, l16 = lane & 15;
#pragma unroll
    for (int tm = 0; tm < 2; tm++)
#pragma unroll
        for (int tn = 0; tn < 4; tn++)
#pragma unroll
            for (int i = 0; i < 4; i++) {
                int r = r0 + wm + tm * 16 + quad * 4 + i;
                int d = wn + tn * 16 + l16;
                int bb = r >> 10, c = r & 1023;
                float xv = fmaxf(accx[tm][tn][i], 0.f);
                float g = 1.f / (1.f + expf(-accg[tm][tn][i]));
                float hv = h[((size_t)c * BB + bb) * DD + d];
                o[((size_t)c * BB + bb) * DD + d] = xv * g + (1.f - g) * hv;
            }
}

extern "C" void kernel_launch(void* const* d_in, const int* in_sizes, int n_in,
                              void* d_out, int out_size, void* d_ws, size_t ws_size,
                              hipStream_t stream) {
    const float* h = (const float*)d_in[0];
    const int* h_mask = (const int*)d_in[1];
    const float* B_t = (const float*)d_in[2];
    const float* W1w = (const float*)d_in[3];
    const float* W1b = (const float*)d_in[4];
    const float* W2w = (const float*)d_in[5];
    const float* W2b = (const float*)d_in[6];
    const float* gp = (const float*)d_in[7];
    const float* Wrw = (const float*)d_in[8];
    const float* Wgw = (const float*)d_in[9];
    float* o = (float*)d_out;
    float* Bnew = o + (size_t)CC * BB * DD;  // output 1 region

    char* ws = (char*)d_ws;
    size_t off = 0;
    auto alloc = [&](size_t bytes) { void* p = ws + off; off += bytes; return p; };
    unsigned short* h_bc = (unsigned short*)alloc((size_t)BB * CC * DD * 2);
    unsigned short* h_bT = (unsigned short*)alloc((size_t)BB * DD * CC * 2);
    unsigned short* h1 = (unsigned short*)alloc((size_t)BB * CC * DD * 2);
    unsigned short* h2 = (unsigned short*)alloc((size_t)BB * CC * DD * 2);
    unsigned short* w1t = (unsigned short*)alloc((size_t)DD * DD * 2);
    unsigned short* w2t = (unsigned short*)alloc((size_t)DD * DD * 2);
    unsigned short* wrt = (unsigned short*)alloc((size_t)DD * 4 * DD * 2);
    unsigned short* wgt = (unsigned short*)alloc((size_t)DD * 4 * DD * 2);
    unsigned short* Bt2 = (unsigned short*)alloc((size_t)BB * CC * CC * 2);
    unsigned short* Bt1T = (unsigned short*)alloc((size_t)BB * CC * CC * 2);
    // union region: phase 1 = BtTh (transposed bf16 B_t, 32MB);
    // phase 2 (after Bt1T is built) = Btt (32MB) + mbuf (16MB)
    char* U = (char*)alloc((size_t)48 * 1024 * 1024);
    unsigned short* BtTh = (unsigned short*)U;
    unsigned short* Btt = (unsigned short*)U;
    unsigned short* mbuf = (unsigned short*)(U + (size_t)32 * 1024 * 1024);

    prep_h<<<dim3(16, 2, 16), 256, 0, stream>>>(h, h_bc, h_bT);
    prep_w<<<dim3(256), 256, 0, stream>>>(W1w, W2w, Wrw, Wgw, w1t, w2t, wrt, wgt);
    gemm_h12<<<dim3(128, 1, 2), 256, 0, stream>>>(h_bc, w1t, w2t, W1b, W2b, h1, h2);
    softmax_row_t<float><<<dim3(1024, 16), 256, 0, stream>>>(B_t, h_mask, Bt2);      // axis=2 -> (b,i,k)
    transpose_bt<<<dim3(16, 16, 16), 256, 0, stream>>>(B_t, BtTh);                   // (b,j,i) bf16
    softmax_row_t<unsigned short><<<dim3(1024, 16), 256, 0, stream>>>(BtTh, h_mask, Bt1T);  // axis=1 -> (b,j,k)
    gemm_bnew<<<dim3(8, 8, 16), 256, 0, stream>>>(Bt2, Bt1T, h1, h2, gp, Bnew);
    softmax_row_t<float><<<dim3(1024, 16), 256, 0, stream>>>(Bnew, h_mask, Btt);     // axis=2 on B_new
    gemm_htmp<<<dim3(16, 1, 16), 256, 0, stream>>>(Btt, h_bT, h, mbuf);
    gemm_gate<<<dim3(256), 256, 0, stream>>>(mbuf, wrt, wgt, h, o);
}

// Round 3
// 262.260 us; speedup vs baseline: 1.8629x; 1.1552x over previous
//
#include <hip/hip_runtime.h>
#include <hip/hip_bf16.h>
#include <math.h>

#define CC 1024
#define BB 16
#define DD 128
#define NEGV -1e30f
#define MP 264  // m' LDS row stride: 2*128 + 8 pad (conflict-free b128 reads)

typedef __attribute__((ext_vector_type(4))) float floatx4;
typedef __attribute__((ext_vector_type(8))) __bf16 bf16x8;
typedef __attribute__((ext_vector_type(8))) int intx8;

__device__ __forceinline__ unsigned short f2bf(float x) {
    unsigned int u = __float_as_uint(x);
    u = (u + 0x7FFFu + ((u >> 16) & 1u)) >> 16;
    return (unsigned short)u;
}
__device__ __forceinline__ float bf2f(unsigned short v) {
    return __uint_as_float((unsigned int)v << 16);
}

// ---------------- prep: h (c,b,d) fp32 -> h_bc (b,c,d) bf16, h_bT (b,d,c) bf16
__global__ __launch_bounds__(256) void prep_h(const float* __restrict__ h,
                                              unsigned short* __restrict__ h_bc,
                                              unsigned short* __restrict__ h_bT) {
    __shared__ float tile[64][65];
    const int c0 = blockIdx.x * 64, d0 = blockIdx.y * 64, b = blockIdx.z;
    const int tx = threadIdx.x & 63, ty = threadIdx.x >> 6;
#pragma unroll
    for (int i = 0; i < 16; i++) {
        int cl = ty + i * 4;
        float v = h[((size_t)(c0 + cl) * BB + b) * DD + d0 + tx];
        tile[cl][tx] = v;
        h_bc[((size_t)b * CC + c0 + cl) * DD + d0 + tx] = f2bf(v);
    }
    __syncthreads();
#pragma unroll
    for (int i = 0; i < 16; i++) {
        int dl = ty + i * 4;
        h_bT[((size_t)b * DD + d0 + dl) * CC + c0 + tx] = f2bf(tile[tx][dl]);
    }
}

// ---------------- prep: cast W1/W2; build combined gate weights
// m@W = h*(W0+W3) + ht*(W1-W3) + (h.ht)*W2  -> wc[(g*3+p)*128 + d][k], K=384
__global__ __launch_bounds__(256) void prep_w(const float* __restrict__ w1, const float* __restrict__ w2,
                                              const float* __restrict__ wr, const float* __restrict__ wg,
                                              unsigned short* __restrict__ o1, unsigned short* __restrict__ o2,
                                              unsigned short* __restrict__ wc) {
    int i = blockIdx.x * 256 + threadIdx.x;  // 0..16383
    int d = i >> 7, k = i & 127;
    o1[i] = f2bf(w1[i]);
    o2[i] = f2bf(w2[i]);
    const float* pr = wr + (size_t)d * 512;
    const float* pg = wg + (size_t)d * 512;
    wc[(size_t)(0 * 128 + d) * 128 + k] = f2bf(pr[k] + pr[384 + k]);
    wc[(size_t)(1 * 128 + d) * 128 + k] = f2bf(pr[128 + k] - pr[384 + k]);
    wc[(size_t)(2 * 128 + d) * 128 + k] = f2bf(pr[256 + k]);
    wc[(size_t)(3 * 128 + d) * 128 + k] = f2bf(pg[k] + pg[384 + k]);
    wc[(size_t)(4 * 128 + d) * 128 + k] = f2bf(pg[128 + k] - pg[384 + k]);
    wc[(size_t)(5 * 128 + d) * 128 + k] = f2bf(pg[256 + k]);
}

// ---------------- transpose B_t (b,i,j) fp32 -> (b,j,i) bf16
__global__ __launch_bounds__(256) void transpose_bt(const float* __restrict__ B_t,
                                                    unsigned short* __restrict__ out) {
    __shared__ float tile[64][65];
    const int b = blockIdx.z, i0 = blockIdx.x * 64, j0 = blockIdx.y * 64;
    const int tx = threadIdx.x & 63, ty = threadIdx.x >> 6;
    const float* src = B_t + (size_t)b * CC * CC;
    unsigned short* dst = out + (size_t)b * CC * CC;
#pragma unroll
    for (int r = ty; r < 64; r += 4) tile[r][tx] = src[(size_t)(i0 + r) * CC + j0 + tx];
    __syncthreads();
#pragma unroll
    for (int r = ty; r < 64; r += 4)
        dst[(size_t)(j0 + r) * CC + i0 + tx] = f2bf(tile[tx][r]);
}

// ---------------- async staging: rows of 128 BYTES (8x16B chunks), XOR-swizzled.
// LDS chunk (r,c) holds global chunk c^(r&7) of row r. NCH = rows*8.
template <int NCH>
__device__ __forceinline__ void stage_async_b(void* dst, const void* src, int ld_bytes) {
    const int w = threadIdx.x >> 6, lane = threadIdx.x & 63;
#pragma unroll
    for (int base = w * 64; base < NCH; base += 256) {
        int ch = base + lane;
        int r = ch >> 3, c = ch & 7;
        int cg = c ^ (r & 7);
        __builtin_amdgcn_global_load_lds(
            (const __attribute__((address_space(1))) void*)((const unsigned char*)src + (size_t)r * ld_bytes + cg * 16),
            (__attribute__((address_space(3))) void*)((unsigned char*)dst + (size_t)base * 16),
            16, 0, 0);
    }
}

// wave computes TM x TN 16x16 tiles over one BK=64 swizzled bf16 LDS tile
template <int TM, int TN>
__device__ __forceinline__ void mfma_tile(const unsigned short (*As)[64], const unsigned short (*Bs)[64],
                                          int arow0, int bcol0, floatx4 (&acc)[TM][TN]) {
    const int lane = threadIdx.x & 63;
    const int l16 = lane & 15, quad = lane >> 4;
    const int sw = l16 & 7;
#pragma unroll
    for (int kk = 0; kk < 2; ++kk) {
        bf16x8 a[TM], b[TN];
#pragma unroll
        for (int tm = 0; tm < TM; tm++)
            a[tm] = *(const bf16x8*)(&As[arow0 + tm * 16 + l16][((kk * 4 + quad) ^ sw) * 8]);
#pragma unroll
        for (int tn = 0; tn < TN; tn++)
            b[tn] = *(const bf16x8*)(&Bs[bcol0 + tn * 16 + l16][((kk * 4 + quad) ^ sw) * 8]);
#pragma unroll
        for (int tm = 0; tm < TM; tm++)
#pragma unroll
            for (int tn = 0; tn < TN; tn++)
                acc[tm][tn] = __builtin_amdgcn_mfma_f32_16x16x32_bf16(a[tm], b[tn], acc[tm][tn], 0, 0, 0);
    }
}

// A from padded (unswizzled) m' LDS, B from swizzled tile
__device__ __forceinline__ void mfma_mixed(const unsigned short* mBase, const unsigned short (*Bs)[64],
                                           int arow0, int bcol0, floatx4 (&acc)[2][4]) {
    const int lane = threadIdx.x & 63;
    const int l16 = lane & 15, quad = lane >> 4;
    const int sw = l16 & 7;
#pragma unroll
    for (int kk = 0; kk < 2; ++kk) {
        bf16x8 a[2], bfr[4];
#pragma unroll
        for (int tm = 0; tm < 2; tm++)
            a[tm] = *(const bf16x8*)(mBase + (size_t)(arow0 + tm * 16 + l16) * MP + kk * 32 + quad * 8);
#pragma unroll
        for (int tn = 0; tn < 4; tn++)
            bfr[tn] = *(const bf16x8*)(&Bs[bcol0 + tn * 16 + l16][((kk * 4 + quad) ^ sw) * 8]);
#pragma unroll
        for (int tm = 0; tm < 2; tm++)
#pragma unroll
            for (int tn = 0; tn < 4; tn++)
                acc[tm][tn] = __builtin_amdgcn_mfma_f32_16x16x32_bf16(a[tm], bfr[tn], acc[tm][tn], 0, 0, 0);
    }
}

// ---------------- h1/h2: relu(h_bc @ W^T + bias), M=16384 N=128 K=128
__global__ __launch_bounds__(256) void gemm_h12(const unsigned short* __restrict__ h_bc,
                                                const unsigned short* __restrict__ w1t,
                                                const unsigned short* __restrict__ w2t,
                                                const float* __restrict__ b1, const float* __restrict__ b2,
                                                unsigned short* __restrict__ h1, unsigned short* __restrict__ h2) {
    __shared__ unsigned short As[128][64];
    __shared__ unsigned short Bs[128][64];
    const unsigned short* W = blockIdx.z ? w2t : w1t;
    const float* bias = blockIdx.z ? b2 : b1;
    unsigned short* out = blockIdx.z ? h2 : h1;
    const int r0 = blockIdx.x * 128;
    const int w = threadIdx.x >> 6, lane = threadIdx.x & 63;
    const int wm = (w >> 1) * 64, wn = (w & 1) * 64;
    floatx4 acc[4][4] = {};
    for (int k0 = 0; k0 < DD; k0 += 64) {
        stage_async_b<1024>(As, h_bc + (size_t)r0 * DD + k0, DD * 2);
        stage_async_b<1024>(Bs, W + k0, DD * 2);
        __syncthreads();
        mfma_tile<4, 4>(As, Bs, wm, wn, acc);
        __syncthreads();
    }
    const int quad = lane >> 4, l16 = lane & 15;
#pragma unroll
    for (int tm = 0; tm < 4; tm++)
#pragma unroll
        for (int tn = 0; tn < 4; tn++)
#pragma unroll
            for (int i = 0; i < 4; i++) {
                int row = r0 + wm + tm * 16 + quad * 4 + i;
                int col = wn + tn * 16 + l16;
                float v = acc[tm][tn][i] + bias[col];
                out[(size_t)row * DD + col] = f2bf(fmaxf(v, 0.f));
            }
}

// ---------------- masked row softmax; T in {float, ushort(bf16)}; out bf16 or fp8(x256)
__device__ __forceinline__ void load4(const float* p, float* x) {
    float4 v = *(const float4*)p;
    x[0] = v.x; x[1] = v.y; x[2] = v.z; x[3] = v.w;
}
__device__ __forceinline__ void load4(const unsigned short* p, float* x) {
    ushort4 v = *(const ushort4*)p;
    x[0] = bf2f(v.x); x[1] = bf2f(v.y); x[2] = bf2f(v.z); x[3] = bf2f(v.w);
}

template <typename T, bool F8>
__global__ __launch_bounds__(256) void softmax_row_t(const T* __restrict__ src, const int* __restrict__ mask,
                                                     void* __restrict__ dstv) {
    const int b = blockIdx.y, i = blockIdx.x;
    const int t = threadIdx.x;
    float x[4];
    load4(src + ((size_t)b * CC + i) * CC + t * 4, x);
    const int4 mv = *(const int4*)(mask + b * CC + t * 4);
    if (mv.x == 0) x[0] = NEGV;
    if (mv.y == 0) x[1] = NEGV;
    if (mv.z == 0) x[2] = NEGV;
    if (mv.w == 0) x[3] = NEGV;
    float mx = fmaxf(fmaxf(x[0], x[1]), fmaxf(x[2], x[3]));
    __shared__ float rm[4], rs[4];
    const int w = t >> 6, lane = t & 63;
#pragma unroll
    for (int off = 32; off; off >>= 1) mx = fmaxf(mx, __shfl_xor(mx, off, 64));
    if (lane == 0) rm[w] = mx;
    __syncthreads();
    mx = fmaxf(fmaxf(rm[0], rm[1]), fmaxf(rm[2], rm[3]));
    float e[4], s = 0.f;
#pragma unroll
    for (int u = 0; u < 4; u++) { e[u] = expf(x[u] - mx); s += e[u]; }
#pragma unroll
    for (int off = 32; off; off >>= 1) s += __shfl_xor(s, off, 64);
    if (lane == 0) rs[w] = s;
    __syncthreads();
    s = rs[0] + rs[1] + rs[2] + rs[3];
    const float inv = 1.f / s;
    const size_t base4 = (((size_t)b * CC + i) * CC) >> 2;
    if constexpr (F8) {
        const float s2 = inv * 256.f;  // scale into e4m3 normal range; max 256 < 448
        int pk = __builtin_amdgcn_cvt_pk_fp8_f32(e[0] * s2, e[1] * s2, 0, false);
        pk = __builtin_amdgcn_cvt_pk_fp8_f32(e[2] * s2, e[3] * s2, pk, true);
        ((int*)dstv)[base4 + t] = pk;
    } else {
        ushort4 o4;
        o4.x = f2bf(e[0] * inv); o4.y = f2bf(e[1] * inv);
        o4.z = f2bf(e[2] * inv); o4.w = f2bf(e[3] * inv);
        ((ushort4*)dstv)[base4 + t] = o4;
    }
}

// ---------------- B_new = h1@h2^T + gamma * Bt2@Bt1 (fp8-MX K=128 for B_1)
// XCD-aware mapping: xcd=flat%8 owns batches {2x, 2x+1} -> per-XCD L2 working set ~2.5MB
__global__ __launch_bounds__(256) void gemm_bnew(const unsigned char* __restrict__ Af8,
                                                 const unsigned char* __restrict__ Bf8,
                                                 const unsigned short* __restrict__ h1,
                                                 const unsigned short* __restrict__ h2,
                                                 const float* __restrict__ gp, float* __restrict__ Bnew) {
    __shared__ __align__(16) unsigned char As[128 * 128];
    __shared__ __align__(16) unsigned char Bs[128 * 128];
    const int flat = blockIdx.x;
    const int x = flat & 7, s = flat >> 3;
    const int bb = x * 2 + (s >> 6);
    const int t = s & 63;
    const int i0 = (t >> 3) * 128, j0 = (t & 7) * 128;
    const unsigned char* A1 = Af8 + (size_t)bb * CC * CC + (size_t)i0 * CC;
    const unsigned char* B1 = Bf8 + (size_t)bb * CC * CC + (size_t)j0 * CC;
    const int w = threadIdx.x >> 6, lane = threadIdx.x & 63;
    const int wm = (w >> 1) * 64, wn = (w & 1) * 64;
    const int l16 = lane & 15, quad = lane >> 4;
    floatx4 acc[4][4] = {};
    const int sA = l16 & 7;
    const int c1 = (2 * quad) ^ sA;  // swizzled chunk of global chunk 2q
    for (int k0 = 0; k0 < CC; k0 += 128) {  // B_1: MX-fp8, one 16x16x128 MFMA per tile
        stage_async_b<1024>(As, A1 + k0, CC);
        stage_async_b<1024>(Bs, B1 + k0, CC);
        __syncthreads();
        intx8 a[4], bfr[4];
#pragma unroll
        for (int tm = 0; tm < 4; tm++) {
            const unsigned char* p = As + (size_t)(wm + tm * 16 + l16) * 128;
            int4 lo = *(const int4*)(p + c1 * 16);
            int4 hi = *(const int4*)(p + (c1 ^ 1) * 16);
            a[tm] = intx8{lo.x, lo.y, lo.z, lo.w, hi.x, hi.y, hi.z, hi.w};
        }
#pragma unroll
        for (int tn = 0; tn < 4; tn++) {
            const unsigned char* p = Bs + (size_t)(wn + tn * 16 + l16) * 128;
            int4 lo = *(const int4*)(p + c1 * 16);
            int4 hi = *(const int4*)(p + (c1 ^ 1) * 16);
            bfr[tn] = intx8{lo.x, lo.y, lo.z, lo.w, hi.x, hi.y, hi.z, hi.w};
        }
#pragma unroll
        for (int tm = 0; tm < 4; tm++)
#pragma unroll
            for (int tn = 0; tn < 4; tn++)
                acc[tm][tn] = __builtin_amdgcn_mfma_scale_f32_16x16x128_f8f6f4(
                    a[tm], bfr[tn], acc[tm][tn], 0, 0, 0, 119, 0, 119);  // 2^-8 * 2^-8 undoes 256*256
        __syncthreads();
    }
    const float gm = gp[0];
#pragma unroll
    for (int tm = 0; tm < 4; tm++)
#pragma unroll
        for (int tn = 0; tn < 4; tn++) acc[tm][tn] *= gm;
    const unsigned short* A2 = h1 + (size_t)bb * CC * DD + (size_t)i0 * DD;
    const unsigned short* B2 = h2 + (size_t)bb * CC * DD + (size_t)j0 * DD;
    for (int k0 = 0; k0 < DD; k0 += 64) {  // B_0: bf16, K=128
        stage_async_b<1024>(As, A2 + k0, DD * 2);
        stage_async_b<1024>(Bs, B2 + k0, DD * 2);
        __syncthreads();
        mfma_tile<4, 4>((const unsigned short(*)[64])As, (const unsigned short(*)[64])Bs, wm, wn, acc);
        __syncthreads();
    }
    float* out = Bnew + (size_t)bb * CC * CC;
#pragma unroll
    for (int tm = 0; tm < 4; tm++)
#pragma unroll
        for (int tn = 0; tn < 4; tn++)
#pragma unroll
            for (int i = 0; i < 4; i++) {
                int row = i0 + wm + tm * 16 + quad * 4 + i;
                int col = j0 + wn + tn * 16 + l16;
                float v = acc[tm][tn][i];
                if (row == col) v = 0.f;
                out[(size_t)row * CC + col] = v;
            }
}

// ---------------- fused: h_tmp = Btt@h_bT^T; m'=[ht, h.ht] in LDS; h from h_bc;
// x=relu(.@WrC), g=sigmoid(.@WgC), o = x*g + (1-g)*h
__global__ __launch_bounds__(256) void gemm_fuse(const unsigned short* __restrict__ Btt,
                                                 const unsigned short* __restrict__ h_bT,
                                                 const unsigned short* __restrict__ h_bc,
                                                 const float* __restrict__ h,
                                                 const unsigned short* __restrict__ wc,
                                                 float* __restrict__ o) {
    __shared__ unsigned short mPb[64 * MP];       // 33 KB
    __shared__ unsigned short S1[64][64];         // 8 KB
    __shared__ unsigned short S2[128][64];        // 16 KB
    const int b = blockIdx.y, i0 = blockIdx.x * 64;
    const int w = threadIdx.x >> 6, lane = threadIdx.x & 63;
    const int wm = (w >> 1) * 32, wn = (w & 1) * 64;
    const int quad = lane >> 4, l16 = lane & 15;
    floatx4 acc[2][4] = {};
    const unsigned short* A = Btt + (size_t)b * CC * CC + (size_t)i0 * CC;
    const unsigned short* Bt = h_bT + (size_t)b * DD * CC;
    for (int k0 = 0; k0 < CC; k0 += 64) {
        stage_async_b<512>(S1, A + k0, CC * 2);
        stage_async_b<1024>(S2, Bt + k0, CC * 2);
        __syncthreads();
        mfma_tile<2, 4>(S1, S2, wm, wn, acc);
        __syncthreads();
    }
    floatx4 hv[2][4];
#pragma unroll
    for (int tm = 0; tm < 2; tm++)
#pragma unroll
        for (int tn = 0; tn < 4; tn++)
#pragma unroll
            for (int i = 0; i < 4; i++) {
                int row = wm + tm * 16 + quad * 4 + i;
                int d = wn + tn * 16 + l16;
                float hvv = h[((size_t)(i0 + row) * BB + b) * DD + d];
                hv[tm][tn][i] = hvv;
                float ht = acc[tm][tn][i];
                mPb[row * MP + d] = f2bf(ht);
                mPb[row * MP + 128 + d] = f2bf(hvv * ht);
            }
    __syncthreads();
    floatx4 ar[2][4] = {}, ag[2][4] = {};
    for (int g = 0; g < 2; ++g) {
        auto& av = g ? ag : ar;
        for (int p = 0; p < 3; ++p)
            for (int k0 = 0; k0 < 128; k0 += 64) {
                if (p == 0) stage_async_b<512>(S1, h_bc + ((size_t)b * CC + i0) * DD + k0, DD * 2);
                stage_async_b<1024>(S2, wc + (size_t)(g * 3 + p) * DD * DD + k0, DD * 2);
                __syncthreads();
                if (p == 0) mfma_tile<2, 4>(S1, S2, wm, wn, av);
                else mfma_mixed(mPb + (p - 1) * 128 + k0, S2, wm, wn, av);
                __syncthreads();
            }
    }
#pragma unroll
    for (int tm = 0; tm < 2; tm++)
#pragma unroll
        for (int tn = 0; tn < 4; tn++)
#pragma unroll
            for (int i = 0; i < 4; i++) {
                int row = wm + tm * 16 + quad * 4 + i;
                int d = wn + tn * 16 + l16;
                float xv = fmaxf(ar[tm][tn][i], 0.f);
                float gv = 1.f / (1.f + expf(-ag[tm][tn][i]));
                o[((size_t)(i0 + row) * BB + b) * DD + d] = xv * gv + (1.f - gv) * hv[tm][tn][i];
            }
}

extern "C" void kernel_launch(void* const* d_in, const int* in_sizes, int n_in,
                              void* d_out, int out_size, void* d_ws, size_t ws_size,
                              hipStream_t stream) {
    const float* h = (const float*)d_in[0];
    const int* h_mask = (const int*)d_in[1];
    const float* B_t = (const float*)d_in[2];
    const float* W1w = (const float*)d_in[3];
    const float* W1b = (const float*)d_in[4];
    const float* W2w = (const float*)d_in[5];
    const float* W2b = (const float*)d_in[6];
    const float* gp = (const float*)d_in[7];
    const float* Wrw = (const float*)d_in[8];
    const float* Wgw = (const float*)d_in[9];
    float* o = (float*)d_out;
    float* Bnew = o + (size_t)CC * BB * DD;

    char* ws = (char*)d_ws;
    size_t off = 0;
    auto alloc = [&](size_t bytes) { void* p = ws + off; off += bytes; return p; };
    unsigned short* h_bc = (unsigned short*)alloc((size_t)BB * CC * DD * 2);
    unsigned short* h_bT = (unsigned short*)alloc((size_t)BB * DD * CC * 2);
    unsigned short* h1 = (unsigned short*)alloc((size_t)BB * CC * DD * 2);
    unsigned short* h2 = (unsigned short*)alloc((size_t)BB * CC * DD * 2);
    unsigned short* w1t = (unsigned short*)alloc((size_t)DD * DD * 2);
    unsigned short* w2t = (unsigned short*)alloc((size_t)DD * DD * 2);
    unsigned short* wc = (unsigned short*)alloc((size_t)6 * DD * DD * 2);
    unsigned char* Bt2f8 = (unsigned char*)alloc((size_t)BB * CC * CC);
    unsigned char* Bt1Tf8 = (unsigned char*)alloc((size_t)BB * CC * CC);
    // union region: phase 1 = BtTh (bf16 B_t^T); phase 2 = Btt (bf16 softmax(B_new))
    char* U = (char*)alloc((size_t)BB * CC * CC * 2);
    unsigned short* BtTh = (unsigned short*)U;
    unsigned short* Btt = (unsigned short*)U;

    prep_h<<<dim3(16, 2, 16), 256, 0, stream>>>(h, h_bc, h_bT);
    prep_w<<<dim3(64), 256, 0, stream>>>(W1w, W2w, Wrw, Wgw, w1t, w2t, wc);
    gemm_h12<<<dim3(128, 1, 2), 256, 0, stream>>>(h_bc, w1t, w2t, W1b, W2b, h1, h2);
    softmax_row_t<float, true><<<dim3(1024, 16), 256, 0, stream>>>(B_t, h_mask, Bt2f8);       // axis=2
    transpose_bt<<<dim3(16, 16, 16), 256, 0, stream>>>(B_t, BtTh);
    softmax_row_t<unsigned short, true><<<dim3(1024, 16), 256, 0, stream>>>(BtTh, h_mask, Bt1Tf8);  // axis=1
    gemm_bnew<<<dim3(1024), 256, 0, stream>>>(Bt2f8, Bt1Tf8, h1, h2, gp, Bnew);
    softmax_row_t<float, false><<<dim3(1024, 16), 256, 0, stream>>>(Bnew, h_mask, Btt);       // axis=2 on B_new
    gemm_fuse<<<dim3(16, 16), 256, 0, stream>>>(Btt, h_bT, h_bc, h, wc, o);
}

// Round 4
// 238.112 us; speedup vs baseline: 2.0518x; 1.1014x over previous
//
#include <hip/hip_runtime.h>
#include <hip/hip_bf16.h>
#include <math.h>

#define CC 1024
#define BB 16
#define DD 128
#define NEGV -1e30f
#define MP 392  // m' LDS row stride: 3*128 + 8 pad (16B-aligned rows)

typedef __attribute__((ext_vector_type(4))) float floatx4;
typedef __attribute__((ext_vector_type(8))) __bf16 bf16x8;
typedef __attribute__((ext_vector_type(8))) int intx8;

__device__ __forceinline__ unsigned short f2bf(float x) {
    unsigned int u = __float_as_uint(x);
    u = (u + 0x7FFFu + ((u >> 16) & 1u)) >> 16;
    return (unsigned short)u;
}
__device__ __forceinline__ float bf2f(unsigned short v) {
    return __uint_as_float((unsigned int)v << 16);
}

// ---------------- prep: h (c,b,d) fp32 -> h_bc (b,c,d) bf16, h_bT (b,d,c) bf16
__global__ __launch_bounds__(256) void prep_h(const float* __restrict__ h,
                                              unsigned short* __restrict__ h_bc,
                                              unsigned short* __restrict__ h_bT) {
    __shared__ float tile[64][65];
    const int c0 = blockIdx.x * 64, d0 = blockIdx.y * 64, b = blockIdx.z;
    const int tx = threadIdx.x & 63, ty = threadIdx.x >> 6;
#pragma unroll
    for (int i = 0; i < 16; i++) {
        int cl = ty + i * 4;
        float v = h[((size_t)(c0 + cl) * BB + b) * DD + d0 + tx];
        tile[cl][tx] = v;
        h_bc[((size_t)b * CC + c0 + cl) * DD + d0 + tx] = f2bf(v);
    }
    __syncthreads();
#pragma unroll
    for (int i = 0; i < 16; i++) {
        int dl = ty + i * 4;
        h_bT[((size_t)b * DD + d0 + dl) * CC + c0 + tx] = f2bf(tile[tx][dl]);
    }
}

// ---------------- prep: cast W1/W2; build combined gate weights
// panels per gate g: p0 = W1-W3 (for ht), p1 = W2 (for h.ht), p2 = W0+W3 (for h)
__global__ __launch_bounds__(256) void prep_w(const float* __restrict__ w1, const float* __restrict__ w2,
                                              const float* __restrict__ wr, const float* __restrict__ wg,
                                              unsigned short* __restrict__ o1, unsigned short* __restrict__ o2,
                                              unsigned short* __restrict__ wc) {
    int i = blockIdx.x * 256 + threadIdx.x;  // 0..16383
    int d = i >> 7, k = i & 127;
    o1[i] = f2bf(w1[i]);
    o2[i] = f2bf(w2[i]);
    const float* pr = wr + (size_t)d * 512;
    const float* pg = wg + (size_t)d * 512;
    wc[(size_t)(0 * 128 + d) * 128 + k] = f2bf(pr[128 + k] - pr[384 + k]);
    wc[(size_t)(1 * 128 + d) * 128 + k] = f2bf(pr[256 + k]);
    wc[(size_t)(2 * 128 + d) * 128 + k] = f2bf(pr[k] + pr[384 + k]);
    wc[(size_t)(3 * 128 + d) * 128 + k] = f2bf(pg[128 + k] - pg[384 + k]);
    wc[(size_t)(4 * 128 + d) * 128 + k] = f2bf(pg[256 + k]);
    wc[(size_t)(5 * 128 + d) * 128 + k] = f2bf(pg[k] + pg[384 + k]);
}

// ---------------- zero the softmax-denominator accumulators (ws is 0xAA-poisoned)
__global__ __launch_bounds__(256) void zero_stats(float* __restrict__ p) {
    int i = (blockIdx.x * 256 + threadIdx.x) * 4;
    *(float4*)(p + i) = float4{0.f, 0.f, 0.f, 0.f};
}

// ---------------- fused exp+mask dual-layout emit (replaces both input softmaxes)
__global__ __launch_bounds__(256) void expmask_dual(const float* __restrict__ B_t,
                                                    const int* __restrict__ mask,
                                                    unsigned char* __restrict__ Em,
                                                    unsigned char* __restrict__ EmT,
                                                    float* __restrict__ rowsum,
                                                    float* __restrict__ colsum) {
    __shared__ float tile[64][68];
    __shared__ float cpart[16][64];
    const int b = blockIdx.z, i0 = blockIdx.x * 64, j0 = blockIdx.y * 64;
    const int tid = threadIdx.x;
    const int rr = tid >> 4, cc = tid & 15;
    const int4 mj4 = *(const int4*)(mask + b * CC + j0 + cc * 4);
    const int4 mi4 = *(const int4*)(mask + b * CC + i0 + cc * 4);
    const float fj[4] = {mj4.x ? 1.f : 0.f, mj4.y ? 1.f : 0.f, mj4.z ? 1.f : 0.f, mj4.w ? 1.f : 0.f};
    const float fi[4] = {mi4.x ? 1.f : 0.f, mi4.y ? 1.f : 0.f, mi4.z ? 1.f : 0.f, mi4.w ? 1.f : 0.f};
    float cp[4] = {0.f, 0.f, 0.f, 0.f};
#pragma unroll
    for (int p = 0; p < 4; p++) {
        const int r = p * 16 + rr;
        float4 v = *(const float4*)(B_t + ((size_t)b * CC + i0 + r) * CC + j0 + cc * 4);
        float e[4] = {expf(fminf(v.x, 80.f)), expf(fminf(v.y, 80.f)),
                      expf(fminf(v.z, 80.f)), expf(fminf(v.w, 80.f))};
        const float mi_r = mask[b * CC + i0 + r] ? 1.f : 0.f;
        float dsum = 0.f;
#pragma unroll
        for (int u = 0; u < 4; u++) {
            tile[r][cc * 4 + u] = e[u];
            cp[u] += e[u] * mi_r;
            dsum += e[u] * fj[u];
        }
        int pk = __builtin_amdgcn_cvt_pk_fp8_f32(e[0] * fj[0], e[1] * fj[1], 0, false);
        pk = __builtin_amdgcn_cvt_pk_fp8_f32(e[2] * fj[2], e[3] * fj[3], pk, true);
        *(int*)(Em + ((size_t)b * CC + i0 + r) * CC + j0 + cc * 4) = pk;
#pragma unroll
        for (int off = 1; off < 16; off <<= 1) dsum += __shfl_xor(dsum, off, 64);
        if (cc == 0) atomicAdd(&rowsum[b * CC + i0 + r], dsum);
    }
#pragma unroll
    for (int u = 0; u < 4; u++) cpart[rr][cc * 4 + u] = cp[u];
    __syncthreads();
    if (tid < 64) {
        float s = 0.f;
#pragma unroll
        for (int q = 0; q < 16; q++) s += cpart[q][tid];
        atomicAdd(&colsum[b * CC + j0 + tid], s);
    }
#pragma unroll
    for (int p = 0; p < 4; p++) {
        const int r2 = p * 16 + rr;
        float t0 = tile[cc * 4 + 0][r2] * fi[0];
        float t1 = tile[cc * 4 + 1][r2] * fi[1];
        float t2 = tile[cc * 4 + 2][r2] * fi[2];
        float t3 = tile[cc * 4 + 3][r2] * fi[3];
        int pk = __builtin_amdgcn_cvt_pk_fp8_f32(t0, t1, 0, false);
        pk = __builtin_amdgcn_cvt_pk_fp8_f32(t2, t3, pk, true);
        *(int*)(EmT + ((size_t)b * CC + j0 + r2) * CC + i0 + cc * 4) = pk;
    }
}

// ---------------- async staging: rows of 128 BYTES (8x16B chunks), XOR-swizzled
template <int NCH>
__device__ __forceinline__ void stage_async_b(void* dst, const void* src, int ld_bytes) {
    const int w = threadIdx.x >> 6, lane = threadIdx.x & 63;
#pragma unroll
    for (int base = w * 64; base < NCH; base += 256) {
        int ch = base + lane;
        int r = ch >> 3, c = ch & 7;
        int cg = c ^ (r & 7);
        __builtin_amdgcn_global_load_lds(
            (const __attribute__((address_space(1))) void*)((const unsigned char*)src + (size_t)r * ld_bytes + cg * 16),
            (__attribute__((address_space(3))) void*)((unsigned char*)dst + (size_t)base * 16),
            16, 0, 0);
    }
}

template <int TM, int TN>
__device__ __forceinline__ void mfma_tile(const unsigned short (*As)[64], const unsigned short (*Bs)[64],
                                          int arow0, int bcol0, floatx4 (&acc)[TM][TN]) {
    const int lane = threadIdx.x & 63;
    const int l16 = lane & 15, quad = lane >> 4;
    const int sw = l16 & 7;
#pragma unroll
    for (int kk = 0; kk < 2; ++kk) {
        bf16x8 a[TM], b[TN];
#pragma unroll
        for (int tm = 0; tm < TM; tm++)
            a[tm] = *(const bf16x8*)(&As[arow0 + tm * 16 + l16][((kk * 4 + quad) ^ sw) * 8]);
#pragma unroll
        for (int tn = 0; tn < TN; tn++)
            b[tn] = *(const bf16x8*)(&Bs[bcol0 + tn * 16 + l16][((kk * 4 + quad) ^ sw) * 8]);
#pragma unroll
        for (int tm = 0; tm < TM; tm++)
#pragma unroll
            for (int tn = 0; tn < TN; tn++)
                acc[tm][tn] = __builtin_amdgcn_mfma_f32_16x16x32_bf16(a[tm], b[tn], acc[tm][tn], 0, 0, 0);
    }
}

__device__ __forceinline__ void mfma_mixed(const unsigned short* mBase, const unsigned short (*Bs)[64],
                                           int arow0, int bcol0, floatx4 (&acc)[2][4]) {
    const int lane = threadIdx.x & 63;
    const int l16 = lane & 15, quad = lane >> 4;
    const int sw = l16 & 7;
#pragma unroll
    for (int kk = 0; kk < 2; ++kk) {
        bf16x8 a[2], bfr[4];
#pragma unroll
        for (int tm = 0; tm < 2; tm++)
            a[tm] = *(const bf16x8*)(mBase + (size_t)(arow0 + tm * 16 + l16) * MP + kk * 32 + quad * 8);
#pragma unroll
        for (int tn = 0; tn < 4; tn++)
            bfr[tn] = *(const bf16x8*)(&Bs[bcol0 + tn * 16 + l16][((kk * 4 + quad) ^ sw) * 8]);
#pragma unroll
        for (int tm = 0; tm < 2; tm++)
#pragma unroll
            for (int tn = 0; tn < 4; tn++)
                acc[tm][tn] = __builtin_amdgcn_mfma_f32_16x16x32_bf16(a[tm], bfr[tn], acc[tm][tn], 0, 0, 0);
    }
}

// ---------------- h1/h2: relu(h_bc @ W^T + bias), M=16384 N=128 K=128
__global__ __launch_bounds__(256) void gemm_h12(const unsigned short* __restrict__ h_bc,
                                                const unsigned short* __restrict__ w1t,
                                                const unsigned short* __restrict__ w2t,
                                                const float* __restrict__ b1, const float* __restrict__ b2,
                                                unsigned short* __restrict__ h1, unsigned short* __restrict__ h2) {
    __shared__ unsigned short As[128][64];
    __shared__ unsigned short Bs[128][64];
    const unsigned short* W = blockIdx.z ? w2t : w1t;
    const float* bias = blockIdx.z ? b2 : b1;
    unsigned short* out = blockIdx.z ? h2 : h1;
    const int r0 = blockIdx.x * 128;
    const int w = threadIdx.x >> 6, lane = threadIdx.x & 63;
    const int wm = (w >> 1) * 64, wn = (w & 1) * 64;
    floatx4 acc[4][4] = {};
    for (int k0 = 0; k0 < DD; k0 += 64) {
        stage_async_b<1024>(As, h_bc + (size_t)r0 * DD + k0, DD * 2);
        stage_async_b<1024>(Bs, W + k0, DD * 2);
        __syncthreads();
        mfma_tile<4, 4>(As, Bs, wm, wn, acc);
        __syncthreads();
    }
    const int quad = lane >> 4, l16 = lane & 15;
#pragma unroll
    for (int tm = 0; tm < 4; tm++)
#pragma unroll
        for (int tn = 0; tn < 4; tn++)
#pragma unroll
            for (int i = 0; i < 4; i++) {
                int row = r0 + wm + tm * 16 + quad * 4 + i;
                int col = wn + tn * 16 + l16;
                float v = acc[tm][tn][i] + bias[col];
                out[(size_t)row * DD + col] = f2bf(fmaxf(v, 0.f));
            }
}

// ---------------- masked row softmax on B_new (fp32 in, bf16 out)
__global__ __launch_bounds__(256) void softmax_row(const float* __restrict__ src, const int* __restrict__ mask,
                                                   unsigned short* __restrict__ dst) {
    const int b = blockIdx.y, i = blockIdx.x;
    const int t = threadIdx.x;
    float4 v = *(const float4*)(src + ((size_t)b * CC + i) * CC + t * 4);
    float x[4] = {v.x, v.y, v.z, v.w};
    const int4 mv = *(const int4*)(mask + b * CC + t * 4);
    if (mv.x == 0) x[0] = NEGV;
    if (mv.y == 0) x[1] = NEGV;
    if (mv.z == 0) x[2] = NEGV;
    if (mv.w == 0) x[3] = NEGV;
    float mx = fmaxf(fmaxf(x[0], x[1]), fmaxf(x[2], x[3]));
    __shared__ float rm[4], rs[4];
    const int w = t >> 6, lane = t & 63;
#pragma unroll
    for (int off = 32; off; off >>= 1) mx = fmaxf(mx, __shfl_xor(mx, off, 64));
    if (lane == 0) rm[w] = mx;
    __syncthreads();
    mx = fmaxf(fmaxf(rm[0], rm[1]), fmaxf(rm[2], rm[3]));
    float e[4], s = 0.f;
#pragma unroll
    for (int u = 0; u < 4; u++) { e[u] = expf(x[u] - mx); s += e[u]; }
#pragma unroll
    for (int off = 32; off; off >>= 1) s += __shfl_xor(s, off, 64);
    if (lane == 0) rs[w] = s;
    __syncthreads();
    s = rs[0] + rs[1] + rs[2] + rs[3];
    const float inv = 1.f / s;
    ushort4 o4;
    o4.x = f2bf(e[0] * inv); o4.y = f2bf(e[1] * inv);
    o4.z = f2bf(e[2] * inv); o4.w = f2bf(e[3] * inv);
    *(ushort4*)(dst + ((size_t)b * CC + i) * CC + t * 4) = o4;
}

// ---------------- B_new = h1@h2^T + gamma * rinv.cinv.(Em@EmT^T)
__global__ __launch_bounds__(256) void gemm_bnew(const unsigned char* __restrict__ Af8,
                                                 const unsigned char* __restrict__ Bf8,
                                                 const unsigned short* __restrict__ h1,
                                                 const unsigned short* __restrict__ h2,
                                                 const float* __restrict__ rowsum,
                                                 const float* __restrict__ colsum,
                                                 const float* __restrict__ gp, float* __restrict__ Bnew) {
    __shared__ __align__(16) unsigned char As[128 * 128];
    __shared__ __align__(16) unsigned char Bs[128 * 128];
    const int flat = blockIdx.x;
    const int x = flat & 7, s = flat >> 3;
    const int bb = x * 2 + (s >> 6);
    const int t = s & 63;
    const int i0 = (t >> 3) * 128, j0 = (t & 7) * 128;
    const unsigned char* A1 = Af8 + (size_t)bb * CC * CC + (size_t)i0 * CC;
    const unsigned char* B1 = Bf8 + (size_t)bb * CC * CC + (size_t)j0 * CC;
    const int w = threadIdx.x >> 6, lane = threadIdx.x & 63;
    const int wm = (w >> 1) * 64, wn = (w & 1) * 64;
    const int l16 = lane & 15, quad = lane >> 4;
    floatx4 acc[4][4] = {};
    const int sA = l16 & 7;
    const int c1 = (2 * quad) ^ sA;
    for (int k0 = 0; k0 < CC; k0 += 128) {
        stage_async_b<1024>(As, A1 + k0, CC);
        stage_async_b<1024>(Bs, B1 + k0, CC);
        __syncthreads();
        intx8 a[4], bfr[4];
#pragma unroll
        for (int tm = 0; tm < 4; tm++) {
            const unsigned char* p = As + (size_t)(wm + tm * 16 + l16) * 128;
            int4 lo = *(const int4*)(p + c1 * 16);
            int4 hi = *(const int4*)(p + (c1 ^ 1) * 16);
            a[tm] = intx8{lo.x, lo.y, lo.z, lo.w, hi.x, hi.y, hi.z, hi.w};
        }
#pragma unroll
        for (int tn = 0; tn < 4; tn++) {
            const unsigned char* p = Bs + (size_t)(wn + tn * 16 + l16) * 128;
            int4 lo = *(const int4*)(p + c1 * 16);
            int4 hi = *(const int4*)(p + (c1 ^ 1) * 16);
            bfr[tn] = intx8{lo.x, lo.y, lo.z, lo.w, hi.x, hi.y, hi.z, hi.w};
        }
#pragma unroll
        for (int tm = 0; tm < 4; tm++)
#pragma unroll
            for (int tn = 0; tn < 4; tn++)
                acc[tm][tn] = __builtin_amdgcn_mfma_scale_f32_16x16x128_f8f6f4(
                    a[tm], bfr[tn], acc[tm][tn], 0, 0, 0, 127, 0, 127);
        __syncthreads();
    }
    const float gm = gp[0];
    float cinv[4], rsc[4][4];
#pragma unroll
    for (int tn = 0; tn < 4; tn++) cinv[tn] = 1.f / colsum[bb * CC + j0 + wn + tn * 16 + l16];
#pragma unroll
    for (int tm = 0; tm < 4; tm++)
#pragma unroll
        for (int i = 0; i < 4; i++)
            rsc[tm][i] = gm / rowsum[bb * CC + i0 + wm + tm * 16 + quad * 4 + i];
#pragma unroll
    for (int tm = 0; tm < 4; tm++)
#pragma unroll
        for (int tn = 0; tn < 4; tn++)
#pragma unroll
            for (int i = 0; i < 4; i++) acc[tm][tn][i] *= rsc[tm][i] * cinv[tn];
    const unsigned short* A2 = h1 + (size_t)bb * CC * DD + (size_t)i0 * DD;
    const unsigned short* B2 = h2 + (size_t)bb * CC * DD + (size_t)j0 * DD;
    for (int k0 = 0; k0 < DD; k0 += 64) {
        stage_async_b<1024>(As, A2 + k0, DD * 2);
        stage_async_b<1024>(Bs, B2 + k0, DD * 2);
        __syncthreads();
        mfma_tile<4, 4>((const unsigned short(*)[64])As, (const unsigned short(*)[64])Bs, wm, wn, acc);
        __syncthreads();
    }
    float* out = Bnew + (size_t)bb * CC * CC;
#pragma unroll
    for (int tm = 0; tm < 4; tm++)
#pragma unroll
        for (int tn = 0; tn < 4; tn++)
#pragma unroll
            for (int i = 0; i < 4; i++) {
                int row = i0 + wm + tm * 16 + quad * 4 + i;
                int col = j0 + wn + tn * 16 + l16;
                float v = acc[tm][tn][i];
                if (row == col) v = 0.f;
                out[(size_t)row * CC + col] = v;
            }
}

// ---------------- fused: h_tmp GEMM + m'=[ht,h.ht,h] in LDS + dual gate GEMM + blend
__global__ __launch_bounds__(256) void gemm_fuse(const unsigned short* __restrict__ Btt,
                                                 const unsigned short* __restrict__ h_bT,
                                                 const float* __restrict__ h,
                                                 const unsigned short* __restrict__ wc,
                                                 float* __restrict__ o) {
    __shared__ unsigned short mPb[64 * MP];
    __shared__ unsigned short S1[2][64][64];
    __shared__ unsigned short S2[2][128][64];
    __shared__ unsigned short Wb[2][128][64];
    const int b = blockIdx.y, i0 = blockIdx.x * 64;
    const int w = threadIdx.x >> 6, lane = threadIdx.x & 63;
    const int wm = (w >> 1) * 32, wn = (w & 1) * 64;
    const int quad = lane >> 4, l16 = lane & 15;
    floatx4 acc[2][4] = {};
    const unsigned short* A = Btt + (size_t)b * CC * CC + (size_t)i0 * CC;
    const unsigned short* Bt = h_bT + (size_t)b * DD * CC;
    stage_async_b<512>(S1[0], A, CC * 2);
    stage_async_b<1024>(S2[0], Bt, CC * 2);
    for (int k = 0; k < 16; k++) {
        __syncthreads();
        if (k < 15) {
            stage_async_b<512>(S1[(k + 1) & 1], A + (k + 1) * 64, CC * 2);
            stage_async_b<1024>(S2[(k + 1) & 1], Bt + (k + 1) * 64, CC * 2);
        }
        mfma_tile<2, 4>(S1[k & 1], S2[k & 1], wm, wn, acc);
    }
    floatx4 hv[2][4];
#pragma unroll
    for (int tm = 0; tm < 2; tm++)
#pragma unroll
        for (int tn = 0; tn < 4; tn++)
#pragma unroll
            for (int i = 0; i < 4; i++) {
                int row = wm + tm * 16 + quad * 4 + i;
                int d = wn + tn * 16 + l16;
                float hvv = h[((size_t)(i0 + row) * BB + b) * DD + d];
                hv[tm][tn][i] = hvv;
                float ht = acc[tm][tn][i];
                mPb[row * MP + d] = f2bf(ht);
                mPb[row * MP + 128 + d] = f2bf(hvv * ht);
                mPb[row * MP + 256 + d] = f2bf(hvv);
            }
    floatx4 ar[2][4] = {}, ag[2][4] = {};
    stage_async_b<1024>(Wb[0], wc, DD * 2);
    for (int s = 0; s < 12; s++) {
        __syncthreads();
        if (s < 11) {
            const int s1 = s + 1;
            const int pan1 = s1 >> 1;              // (g*3+p) panel index 0..5
            const int k1 = (s1 & 1) * 64;          // half within panel
            stage_async_b<1024>(Wb[s1 & 1], wc + (size_t)pan1 * DD * DD + k1, DD * 2);
        }
        const int pan = s >> 1;
        const int koff = (pan % 3) * 128 + (s & 1) * 64;  // offset into m' K=384
        mfma_mixed(mPb + koff, Wb[s & 1], wm, wn, (s >= 6) ? ag : ar);
    }
#pragma unroll
    for (int tm = 0; tm < 2; tm++)
#pragma unroll
        for (int tn = 0; tn < 4; tn++)
#pragma unroll
            for (int i = 0; i < 4; i++) {
                int row = wm + tm * 16 + quad * 4 + i;
                int d = wn + tn * 16 + l16;
                float xv = fmaxf(ar[tm][tn][i], 0.f);
                float gv = 1.f / (1.f + expf(-ag[tm][tn][i]));
                o[((size_t)(i0 + row) * BB + b) * DD + d] = xv * gv + (1.f - gv) * hv[tm][tn][i];
            }
}

extern "C" void kernel_launch(void* const* d_in, const int* in_sizes, int n_in,
                              void* d_out, int out_size, void* d_ws, size_t ws_size,
                              hipStream_t stream) {
    const float* h = (const float*)d_in[0];
    const int* h_mask = (const int*)d_in[1];
    const float* B_t = (const float*)d_in[2];
    const float* W1w = (const float*)d_in[3];
    const float* W1b = (const float*)d_in[4];
    const float* W2w = (const float*)d_in[5];
    const float* W2b = (const float*)d_in[6];
    const float* gp = (const float*)d_in[7];
    const float* Wrw = (const float*)d_in[8];
    const float* Wgw = (const float*)d_in[9];
    float* o = (float*)d_out;
    float* Bnew = o + (size_t)CC * BB * DD;

    char* ws = (char*)d_ws;
    size_t off = 0;
    auto alloc = [&](size_t bytes) { void* p = ws + off; off += bytes; return p; };
    unsigned short* h_bc = (unsigned short*)alloc((size_t)BB * CC * DD * 2);
    unsigned short* h_bT = (unsigned short*)alloc((size_t)BB * DD * CC * 2);
    unsigned short* h1 = (unsigned short*)alloc((size_t)BB * CC * DD * 2);
    unsigned short* h2 = (unsigned short*)alloc((size_t)BB * CC * DD * 2);
    unsigned short* w1t = (unsigned short*)alloc((size_t)DD * DD * 2);
    unsigned short* w2t = (unsigned short*)alloc((size_t)DD * DD * 2);
    unsigned short* wc = (unsigned short*)alloc((size_t)6 * DD * DD * 2);
    unsigned char* Em = (unsigned char*)alloc((size_t)BB * CC * CC);
    unsigned char* EmT = (unsigned char*)alloc((size_t)BB * CC * CC);
    float* stats = (float*)alloc((size_t)2 * BB * CC * 4);
    float* rowsum = stats;
    float* colsum = stats + (size_t)BB * CC;
    unsigned short* Btt = (unsigned short*)alloc((size_t)BB * CC * CC * 2);

    zero_stats<<<dim3(32), 256, 0, stream>>>(stats);
    expmask_dual<<<dim3(16, 16, 16), 256, 0, stream>>>(B_t, h_mask, Em, EmT, rowsum, colsum);
    prep_h<<<dim3(16, 2, 16), 256, 0, stream>>>(h, h_bc, h_bT);
    prep_w<<<dim3(64), 256, 0, stream>>>(W1w, W2w, Wrw, Wgw, w1t, w2t, wc);
    gemm_h12<<<dim3(128, 1, 2), 256, 0, stream>>>(h_bc, w1t, w2t, W1b, W2b, h1, h2);
    gemm_bnew<<<dim3(1024), 256, 0, stream>>>(Em, EmT, h1, h2, rowsum, colsum, gp, Bnew);
    softmax_row<<<dim3(1024, 16), 256, 0, stream>>>(Bnew, h_mask, Btt);
    gemm_fuse<<<dim3(16, 16), 256, 0, stream>>>(Btt, h_bT, h, wc, o);
}